// Round 5
// baseline (283.258 us; speedup 1.0000x reference)
//
#include <hip/hip_runtime.h>

// EdgeEmbedding: out[i,:] = ete[data[i],:] + segsum(attr_table[flat_attr_ids], attr_seg_ids)[data[i],:]
// N=1e6, D=256, NUM_TYPES=1000, TOTAL_ATTRS=50k, ATTR_NUM=200k. All f32, idx int32.

#define EE_D   256
#define EE_D4  64          // float4s per row
#define EE_NT  1000
#define EE_K   4           // types per build block

typedef float fvec4 __attribute__((ext_vector_type(4)));

// Phase A: one block per EE_K types. 4 waves scan the (seg,id) list with
// coalesced 64-wide loads; one ballot per type; fvec4 per-lane accumulators;
// LDS-combine (wave k reduces type k); add ete; non-atomic comb write.
__global__ __launch_bounds__(256) void ee_build_comb(
        const fvec4* __restrict__ ete,
        const fvec4* __restrict__ attr,
        const int* __restrict__ ids,
        const int* __restrict__ segs,
        fvec4* __restrict__ comb, int na) {
    const int t0   = blockIdx.x * EE_K;
    const int tid  = threadIdx.x;
    const int wave = tid >> 6;
    const int lane = tid & 63;

    fvec4 acc[EE_K];
    #pragma unroll
    for (int k = 0; k < EE_K; ++k) acc[k] = (fvec4)0.f;

    for (int base = wave * 64; base < na; base += 256) {
        int a = base + lane;
        int s = -1, id = 0;
        if (a < na) { s = segs[a]; id = ids[a]; }        // coalesced 256B loads
        #pragma unroll
        for (int k = 0; k < EE_K; ++k) {
            unsigned long long m = __ballot(s == t0 + k);
            while (m) {                                  // ~0.06 matches/type/iter
                int j = __ffsll((long long)m) - 1;
                m &= m - 1;
                int aid = __shfl(id, j);
                acc[k] += attr[(size_t)aid * EE_D4 + lane];  // 1KB coalesced row
            }
        }
    }

    __shared__ fvec4 red[EE_K][4][64];
    #pragma unroll
    for (int k = 0; k < EE_K; ++k) red[k][wave][lane] = acc[k];
    __syncthreads();
    if (wave < EE_K) {                                   // wave k finalizes type t0+k
        int k = wave;
        fvec4 r = red[k][0][lane];
        #pragma unroll
        for (int w = 1; w < 4; ++w) r += red[k][w][lane];
        r += ete[(size_t)(t0 + k) * EE_D4 + lane];
        comb[(size_t)(t0 + k) * EE_D4 + lane] = r;
    }
}

// Phase B: out[r][:] = comb[data[r]][:]. Each wave: one coalesced load of 64
// indices, then 64 fully-unrolled (readlane -> L2 comb load -> 1KB plain store).
// R5 single-variable change: stores are PLAIN (no nontemporal flag).
__global__ __launch_bounds__(256) void ee_gather_out(
        const int* __restrict__ data,
        const fvec4* __restrict__ comb,
        fvec4* __restrict__ out, int n) {
    const int gid  = blockIdx.x * blockDim.x + threadIdx.x;
    const int wave = gid >> 6;
    const int lane = gid & 63;
    const int nw   = (gridDim.x * blockDim.x) >> 6;

    for (int base = wave * 64; base < n; base += nw * 64) {
        int r = base + lane;
        int idx = (r < n) ? __builtin_nontemporal_load(&data[r]) : 0;
        int lim = n - base;
        if (lim >= 64) {
            #pragma unroll                               // j compile-time -> v_readlane
            for (int j = 0; j < 64; ++j) {
                int t = __builtin_amdgcn_readlane(idx, j);
                out[(size_t)(base + j) * EE_D4 + lane] = comb[(size_t)t * EE_D4 + lane];
            }
        } else {
            for (int j = 0; j < lim; ++j) {
                int t = __shfl(idx, j);
                out[(size_t)(base + j) * EE_D4 + lane] = comb[(size_t)t * EE_D4 + lane];
            }
        }
    }
}

extern "C" void kernel_launch(void* const* d_in, const int* in_sizes, int n_in,
                              void* d_out, int out_size, void* d_ws, size_t ws_size,
                              hipStream_t stream) {
    const int*   data          = (const int*)d_in[0];
    const float* attr_table    = (const float*)d_in[1];
    const float* ete           = (const float*)d_in[2];
    const int*   flat_attr_ids = (const int*)d_in[3];
    const int*   attr_seg_ids  = (const int*)d_in[4];
    fvec4* comb = (fvec4*)d_ws;                    // 1000*256 f32 = 1 MB scratch
    int N  = in_sizes[0];                          // 1,000,000 edges
    int TA = in_sizes[3];                          // 50,000 ragged attrs

    ee_build_comb<<<EE_NT / EE_K, 256, 0, stream>>>(
        (const fvec4*)ete, (const fvec4*)attr_table,
        flat_attr_ids, attr_seg_ids, comb, TA);

    ee_gather_out<<<2048, 256, 0, stream>>>(
        data, comb, (fvec4*)d_out, N);
}